// Round 8
// baseline (156.359 us; speedup 1.0000x reference)
//
#include <hip/hip_runtime.h>
#include <hip/hip_bf16.h>
#include <math.h>

#define BB 4
#define MM 1024
#define RR 256
#define HH 16
#define DHH 64
#define DD (HH*DHH)   // 1024

typedef __attribute__((ext_vector_type(8))) short short8;   // 8 bf16 (MFMA A/B frag)
typedef __attribute__((ext_vector_type(4))) float f32x4;    // MFMA C/D frag

static __device__ __forceinline__ unsigned short f2bf(float x) {
    __hip_bfloat16 h = __float2bfloat16(x);
    return *(unsigned short*)&h;
}

#if defined(__has_builtin)
#  if __has_builtin(__builtin_amdgcn_exp2f)
#    define EXP2F(x) __builtin_amdgcn_exp2f(x)
#  endif
#endif
#ifndef EXP2F
#  define EXP2F(x) __expf((x) * 0.6931471805599453f)
#endif

// pack two fp32 -> bf16x2 via round-half-up + v_perm (3 VALU total)
static __device__ __forceinline__ unsigned pack_bf16_rh(float a, float b) {
    unsigned ua = __builtin_bit_cast(unsigned, a) + 0x8000u;
    unsigned ub = __builtin_bit_cast(unsigned, b) + 0x8000u;
    return __builtin_amdgcn_perm(ub, ua, 0x07060302u);   // {lo=ua[31:16], hi=ub[31:16]}
}

// ---------------- Kernel A: V (R x d) fp32 -> VT (d x R) bf16 ----------------
// grid 768 = (R/32)*(d/32)*3, block 256.
__global__ __launch_bounds__(256) void prep_kernel(
    const float* __restrict__ Vq, const float* __restrict__ Vk, const float* __restrict__ Vv,
    __hip_bfloat16* __restrict__ VTq, __hip_bfloat16* __restrict__ VTk,
    __hip_bfloat16* __restrict__ VTv)
{
    const int t   = threadIdx.x;
    const int z   = blockIdx.x / 256;
    const int rem = blockIdx.x % 256;
    const int r0  = (rem & 7) * 32;
    const int d0  = (rem >> 3) * 32;
    const float* V = (z == 0) ? Vq : (z == 1) ? Vk : Vv;
    __hip_bfloat16* VT = (z == 0) ? VTq : (z == 1) ? VTk : VTv;

    __shared__ __hip_bfloat16 Ts[32][33];
    {
        const int row = t >> 3;
        const int c4  = (t & 7) * 4;
        float4 f = *(const float4*)&V[(size_t)(r0 + row) * DD + d0 + c4];
        Ts[row][c4 + 0] = __float2bfloat16(f.x);
        Ts[row][c4 + 1] = __float2bfloat16(f.y);
        Ts[row][c4 + 2] = __float2bfloat16(f.z);
        Ts[row][c4 + 3] = __float2bfloat16(f.w);
    }
    __syncthreads();
    {
        const int orow = t >> 3;
        const int oc4  = (t & 7) * 4;
        union { unsigned short u[4]; uint2 v; } pk;
        #pragma unroll
        for (int i = 0; i < 4; ++i) pk.u[i] = *(unsigned short*)&Ts[oc4 + i][orow];
        *(uint2*)&VT[(size_t)(d0 + orow) * RR + r0 + oc4] = pk.v;
    }
}

// ---------------- Kernel B: MFMA projection v2 ----------------
// grid (B*M/64, H/4, 3), block 256 (4 waves). 64 m x 256 d (4 heads), K=256 in 4x64.
// Reads fp32 P directly (cvt during staging). P re-read factor 4 (was 16).
__global__ __launch_bounds__(256) void svd_gemm(
    const float* __restrict__ Pq, const float* __restrict__ Pk, const float* __restrict__ Pv,
    const __hip_bfloat16* __restrict__ VTq, const __hip_bfloat16* __restrict__ VTk,
    const __hip_bfloat16* __restrict__ VTv,
    const float* __restrict__ bq, const float* __restrict__ bk, const float* __restrict__ bv,
    const int* __restrict__ pos_ids,
    __hip_bfloat16* __restrict__ qout, __hip_bfloat16* __restrict__ kout,
    __hip_bfloat16* __restrict__ vTout)
{
    const int which = blockIdx.z;
    const float* P           = (which == 0) ? Pq : (which == 1) ? Pk : Pv;
    const __hip_bfloat16* VT = (which == 0) ? VTq : (which == 1) ? VTk : VTv;
    const float* bias        = (which == 0) ? bq : (which == 1) ? bk : bv;

    const int hg  = blockIdx.y;               // head group: heads hg*4 .. hg*4+3
    const int bm0 = blockIdx.x * 64;          // flattened b*M + m (64 | 1024, no b-crossing)
    const int b   = bm0 >> 10;
    const int m0  = bm0 & 1023;
    const int tid = threadIdx.x;
    const int lane = tid & 63;
    const int w    = tid >> 6;
    const int l15  = lane & 15;
    const int quad = lane >> 4;

    __shared__ alignas(16) short SM[(64 + 256) * 72];     // As[64][72] + Bs[256][72], 46.1 KB
    short* As = SM;
    short* Bs = SM + 64 * 72;

    f32x4 acc[16];
    #pragma unroll
    for (int dt = 0; dt < 16; ++dt) acc[dt] = (f32x4){0.f, 0.f, 0.f, 0.f};

    for (int kc = 0; kc < 4; ++kc) {
        // ---- stage A: P 64 x 64 fp32 -> bf16 (4 float4 / thread) ----
        #pragma unroll
        for (int i = 0; i < 4; ++i) {
            int u   = tid + i * 256;          // 0..1023 float4 units (16 per row)
            int row = u >> 4;
            int c4  = (u & 15) * 4;
            float4 f = *(const float4*)&P[(size_t)(bm0 + row) * RR + kc * 64 + c4];
            uint2 pk;
            pk.x = pack_bf16_rh(f.x, f.y);
            pk.y = pack_bf16_rh(f.z, f.w);
            *(uint2*)&As[row * 72 + c4] = pk;
        }
        // ---- stage B: VT 256 x 64 bf16 (8 uint4 / thread) ----
        #pragma unroll
        for (int i = 0; i < 8; ++i) {
            int u   = tid + i * 256;          // 0..2047 b128 units (8 per row)
            int row = u >> 3;
            int cg  = (u & 7) * 8;
            *(uint4*)&Bs[row * 72 + cg] =
                *(const uint4*)((const short*)VT + (size_t)(hg * 256 + row) * RR + kc * 64 + cg);
        }
        __syncthreads();

        #pragma unroll
        for (int ks = 0; ks < 2; ++ks) {
            short8 a = *(const short8*)&As[(w * 16 + l15) * 72 + ks * 32 + quad * 8];
            #pragma unroll
            for (int dt = 0; dt < 16; ++dt) {
                short8 bf = *(const short8*)&Bs[(dt * 16 + l15) * 72 + ks * 32 + quad * 8];
                acc[dt] = __builtin_amdgcn_mfma_f32_16x16x32_bf16(a, bf, acc[dt], 0, 0, 0);
            }
        }
        __syncthreads();
    }

    // bias: bias[h*64 + cd] = bias[hg*256 + dt*16 + l15]
    #pragma unroll
    for (int dt = 0; dt < 16; ++dt) {
        float bc = bias[hg * 256 + dt * 16 + l15];
        #pragma unroll
        for (int r = 0; r < 4; ++r) acc[dt][r] += bc;
    }

    if (which < 2) {
        __hip_bfloat16* out = (which == 0) ? qout : kout;
        int pm[4];
        #pragma unroll
        for (int r = 0; r < 4; ++r)
            pm[r] = pos_ids[bm0 + w * 16 + quad * 4 + r];
        float cB[2][4], sB[2][4];                          // [freq-half][r]
        #pragma unroll
        for (int f2 = 0; f2 < 2; ++f2) {
            float invf = __powf(10000.0f, -(float)(f2 * 16 + l15) * (1.0f / 32.0f));
            #pragma unroll
            for (int r = 0; r < 4; ++r) {
                float ang = (float)pm[r] * invf;
                __sincosf(ang, &sB[f2][r], &cB[f2][r]);
            }
        }
        #pragma unroll
        for (int dt = 0; dt < 16; ++dt) {
            const int h  = hg * 4 + (dt >> 2);
            const int cd = (dt & 3) * 16 + l15;
            const int f2 = dt & 1;
            #pragma unroll
            for (int r = 0; r < 4; ++r) {
                float x  = acc[dt][r];
                float xp = acc[dt ^ 2][r];                // rotate-half partner, same head
                float c = cB[f2][r], s = sB[f2][r];
                float val = ((dt & 3) < 2) ? (x * c - xp * s) : (xp * s + x * c);
                int m = m0 + w * 16 + quad * 4 + r;
                out[(((size_t)b * HH + h) * MM + m) * DHH + cd] = __float2bfloat16(val);
            }
        }
    } else {
        // v: transpose 256 d x 64 m through LDS in two 128-row passes -> [b][h][d][m]
        short* Tt = SM;                                    // [128][72]
        #pragma unroll
        for (int pp = 0; pp < 2; ++pp) {
            __syncthreads();
            #pragma unroll
            for (int dt2 = 0; dt2 < 8; ++dt2) {
                int dt = pp * 8 + dt2;
                uint2 pk;
                pk.x = pack_bf16_rh(acc[dt][0], acc[dt][1]);
                pk.y = pack_bf16_rh(acc[dt][2], acc[dt][3]);
                *(uint2*)&Tt[(dt2 * 16 + l15) * 72 + w * 16 + quad * 4] = pk;
            }
            __syncthreads();
            #pragma unroll
            for (int i = 0; i < 4; ++i) {
                int u   = tid + i * 256;      // 0..1023: 128 rows x 8 segs
                int row = u >> 3;
                int seg = u & 7;
                int dl  = pp * 128 + row;     // d-local 0..255
                int h   = hg * 4 + (dl >> 6);
                int din = dl & 63;
                *(uint4*)&vTout[(((size_t)b * HH + h) * DHH + din) * MM + m0 + seg * 8] =
                    *(const uint4*)&Tt[row * 72 + seg * 8];
            }
        }
    }
}

// ---------------- Kernel C: flash attention v3 (unchanged from R7) ----------------
// grid = 512: blockIdx = qt*64 + bh; wave = 32 queries; 128-key chunks.
__global__ __launch_bounds__(256, 2) void attn_kernel(
    const __hip_bfloat16* __restrict__ q, const __hip_bfloat16* __restrict__ k,
    const __hip_bfloat16* __restrict__ vT,
    const int* __restrict__ mask, float* __restrict__ out)
{
    const int bh   = blockIdx.x & 63;
    const int qt   = blockIdx.x >> 6;         // 0..7
    const int b    = bh >> 4;
    const int tid  = threadIdx.x;
    const int lane = tid & 63;
    const int w    = tid >> 6;
    const int l15  = lane & 15;
    const int quad = lane >> 4;
    const int q0   = qt * 128;

    __shared__ alignas(16) __hip_bfloat16 Kt[128][72];
    __shared__ alignas(16) __hip_bfloat16 Vt[64][136];

    const short* kbase = (const short*)k  + (size_t)bh * MM * DHH;
    const short* vbase = (const short*)vT + (size_t)bh * DHH * MM;

    short8 qa[2][2];
    #pragma unroll
    for (int mt = 0; mt < 2; ++mt) {
        const short* qb = (const short*)q +
            ((size_t)bh * MM + q0 + w * 32 + mt * 16 + l15) * DHH + quad * 8;
        qa[mt][0] = *(const short8*)(qb);
        qa[mt][1] = *(const short8*)(qb + 32);
    }

    f32x4 Ot[2][4];
    #pragma unroll
    for (int mt = 0; mt < 2; ++mt)
        #pragma unroll
        for (int dt = 0; dt < 4; ++dt) Ot[mt][dt] = (f32x4){0.f, 0.f, 0.f, 0.f};
    float lsum[2] = {0.f, 0.f};

    const int* maskb = mask + b * MM;
    const int srcbase = (lane & 48) | ((lane & 48) >> 2);
    const float k2 = 0.125f * 1.44269504089f;

    for (int nc = 0; nc < MM / 128; ++nc) {
        const int n0 = nc * 128;
        #pragma unroll
        for (int pass = 0; pass < 4; ++pass) {
            int u   = tid + pass * 256;
            int row = u >> 3;
            int cg  = u & 7;
            *(uint4*)&Kt[row][cg * 8] =
                *(const uint4*)(kbase + (size_t)(n0 + row) * DHH + cg * 8);
        }
        #pragma unroll
        for (int pass = 0; pass < 4; ++pass) {
            int u   = tid + pass * 256;
            int row = u >> 4;
            int c   = u & 15;
            union { uint4 q4; uint2 h2[2]; } vld;
            vld.q4 = *(const uint4*)(vbase + (size_t)row * MM + n0 + c * 8);
            int g  = c >> 3;
            int c6 = c & 7;
            int base0 = g * 64 + (c6 >> 2) * 32 + (c6 & 1) * 16 + ((c6 >> 1) & 1) * 4;
            *(uint2*)&Vt[row][base0]     = vld.h2[0];
            *(uint2*)&Vt[row][base0 + 8] = vld.h2[1];
        }
        __syncthreads();

        unsigned long long bal0 = __ballot(maskb[n0 + lane] != 0);
        unsigned long long bal1 = __ballot(maskb[n0 + 64 + lane] != 0);

        f32x4 S[2][8];
        #pragma unroll
        for (int t = 0; t < 8; ++t) {
            const short* kr = (const short*)&Kt[t * 16 + l15][quad * 8];
            short8 ka0 = *(const short8*)(kr);
            short8 ka1 = *(const short8*)(kr + 32);
            #pragma unroll
            for (int mt = 0; mt < 2; ++mt) {
                f32x4 c = (f32x4){0.f, 0.f, 0.f, 0.f};
                c = __builtin_amdgcn_mfma_f32_16x16x32_bf16(ka0, qa[mt][0], c, 0, 0, 0);
                c = __builtin_amdgcn_mfma_f32_16x16x32_bf16(ka1, qa[mt][1], c, 0, 0, 0);
                S[mt][t] = c;
            }
        }

        #pragma unroll
        for (int t = 0; t < 8; ++t) {
            unsigned bits = (unsigned)((t < 4 ? bal0 : bal1) >> ((t & 3) * 16 + quad * 4));
            #pragma unroll
            for (int r = 0; r < 4; ++r) {
                float sb = ((bits >> r) & 1u) ? 0.0f : -1e30f;
                #pragma unroll
                for (int mt = 0; mt < 2; ++mt) {
                    float e = EXP2F(fmaf(S[mt][t][r], k2, sb));
                    lsum[mt] += e;
                    S[mt][t][r] = e;
                }
            }
        }

        short8 pa[2][4];
        #pragma unroll
        for (int mt = 0; mt < 2; ++mt)
            #pragma unroll
            for (int p = 0; p < 4; ++p) {
                union { unsigned u[4]; short8 s; } pk;
                pk.u[0] = pack_bf16_rh(S[mt][2*p][0],   S[mt][2*p][1]);
                pk.u[1] = pack_bf16_rh(S[mt][2*p][2],   S[mt][2*p][3]);
                pk.u[2] = pack_bf16_rh(S[mt][2*p+1][0], S[mt][2*p+1][1]);
                pk.u[3] = pack_bf16_rh(S[mt][2*p+1][2], S[mt][2*p+1][3]);
                pa[mt][p] = pk.s;
            }

        #pragma unroll
        for (int p = 0; p < 4; ++p) {
            #pragma unroll
            for (int dt = 0; dt < 4; ++dt) {
                short8 vb = *(const short8*)&Vt[dt * 16 + l15][p * 32 + quad * 8];
                #pragma unroll
                for (int mt = 0; mt < 2; ++mt)
                    Ot[mt][dt] = __builtin_amdgcn_mfma_f32_16x16x32_bf16(pa[mt][p], vb, Ot[mt][dt], 0, 0, 0);
            }
        }
        __syncthreads();
    }

    #pragma unroll
    for (int mt = 0; mt < 2; ++mt) {
        float s = lsum[mt];
        s += __shfl_xor(s, 16, 64);
        s += __shfl_xor(s, 32, 64);
        float inv = 1.0f / s;
        float* ob = out + ((size_t)bh * MM + q0 + w * 32 + mt * 16) * DHH;
        #pragma unroll
        for (int r = 0; r < 4; ++r) {
            float ir = __shfl(inv, srcbase + r, 64);
            #pragma unroll
            for (int dt = 0; dt < 4; ++dt)
                ob[(quad * 4 + r) * DHH + dt * 16 + l15] = Ot[mt][dt][r] * ir;
        }
    }
}

extern "C" void kernel_launch(void* const* d_in, const int* in_sizes, int n_in,
                              void* d_out, int out_size, void* d_ws, size_t ws_size,
                              hipStream_t stream) {
    const float* Pq = (const float*)d_in[0];
    const float* Pk = (const float*)d_in[1];
    const float* Pv = (const float*)d_in[2];
    const float* Vq = (const float*)d_in[3];
    const float* Vk = (const float*)d_in[4];
    const float* Vv = (const float*)d_in[5];
    const float* bq = (const float*)d_in[6];
    const float* bk = (const float*)d_in[7];
    const float* bv = (const float*)d_in[8];
    const int* mask = (const int*)d_in[9];
    const int* pos  = (const int*)d_in[10];
    float* out = (float*)d_out;

    const size_t qkv_elems = (size_t)BB * HH * MM * DHH;
    __hip_bfloat16* qb  = (__hip_bfloat16*)d_ws;
    __hip_bfloat16* kb  = qb + qkv_elems;
    __hip_bfloat16* vT  = kb + qkv_elems;
    __hip_bfloat16* VTq = vT + qkv_elems;
    __hip_bfloat16* VTk = VTq + (size_t)DD * RR;
    __hip_bfloat16* VTv = VTk + (size_t)DD * RR;

    prep_kernel<<<768, 256, 0, stream>>>(Vq, Vk, Vv, VTq, VTk, VTv);

    dim3 gG(BB * MM / 64, HH / 4, 3);
    svd_gemm<<<gG, 256, 0, stream>>>(Pq, Pk, Pv, VTq, VTk, VTv, bq, bk, bv, pos,
                                     qb, kb, vT);

    attn_kernel<<<BB * HH * (MM / 128), 256, 0, stream>>>(qb, kb, vT, mask, out);
}

// Round 9
// 143.986 us; speedup vs baseline: 1.0859x; 1.0859x over previous
//
#include <hip/hip_runtime.h>
#include <hip/hip_bf16.h>
#include <math.h>

#define BB 4
#define MM 1024
#define RR 256
#define HH 16
#define DHH 64
#define DD (HH*DHH)   // 1024

typedef __attribute__((ext_vector_type(8))) short short8;   // 8 bf16 (MFMA A/B frag)
typedef __attribute__((ext_vector_type(4))) float f32x4;    // MFMA C/D frag

static __device__ __forceinline__ unsigned short f2bf(float x) {
    __hip_bfloat16 h = __float2bfloat16(x);
    return *(unsigned short*)&h;
}

#if defined(__has_builtin)
#  if __has_builtin(__builtin_amdgcn_exp2f)
#    define EXP2F(x) __builtin_amdgcn_exp2f(x)
#  endif
#endif
#ifndef EXP2F
#  define EXP2F(x) __expf((x) * 0.6931471805599453f)
#endif

// pack two fp32 -> bf16x2 via round-half-up + v_perm (3 VALU total)
static __device__ __forceinline__ unsigned pack_bf16_rh(float a, float b) {
    unsigned ua = __builtin_bit_cast(unsigned, a) + 0x8000u;
    unsigned ub = __builtin_bit_cast(unsigned, b) + 0x8000u;
    return __builtin_amdgcn_perm(ub, ua, 0x07060302u);   // {lo=ua[31:16], hi=ub[31:16]}
}

// ---------------- Kernel A: V (R x d) fp32 -> VT (d x R) bf16 ----------------
// grid 768 = (R/32)*(d/32)*3, block 256.
__global__ __launch_bounds__(256) void prep_kernel(
    const float* __restrict__ Vq, const float* __restrict__ Vk, const float* __restrict__ Vv,
    __hip_bfloat16* __restrict__ VTq, __hip_bfloat16* __restrict__ VTk,
    __hip_bfloat16* __restrict__ VTv)
{
    const int t   = threadIdx.x;
    const int z   = blockIdx.x / 256;
    const int rem = blockIdx.x % 256;
    const int r0  = (rem & 7) * 32;
    const int d0  = (rem >> 3) * 32;
    const float* V = (z == 0) ? Vq : (z == 1) ? Vk : Vv;
    __hip_bfloat16* VT = (z == 0) ? VTq : (z == 1) ? VTk : VTv;

    __shared__ __hip_bfloat16 Ts[32][33];
    {
        const int row = t >> 3;
        const int c4  = (t & 7) * 4;
        float4 f = *(const float4*)&V[(size_t)(r0 + row) * DD + d0 + c4];
        Ts[row][c4 + 0] = __float2bfloat16(f.x);
        Ts[row][c4 + 1] = __float2bfloat16(f.y);
        Ts[row][c4 + 2] = __float2bfloat16(f.z);
        Ts[row][c4 + 3] = __float2bfloat16(f.w);
    }
    __syncthreads();
    {
        const int orow = t >> 3;
        const int oc4  = (t & 7) * 4;
        union { unsigned short u[4]; uint2 v; } pk;
        #pragma unroll
        for (int i = 0; i < 4; ++i) pk.u[i] = *(unsigned short*)&Ts[oc4 + i][orow];
        *(uint2*)&VT[(size_t)(d0 + orow) * RR + r0 + oc4] = pk.v;
    }
}

// ---------------- Kernel B: MFMA projection v3 — direct-A, LDS only for V^T --------
// grid (B*M/128, H/2, 3), block 256 (4 waves). 128 m x 128 d (2 heads), K=256 in 2x128.
// A-frags loaded straight from fp32 P (lane-shaped 2x dwordx4 + v_perm cvt): no A
// staging, no A barriers. B: VT chunk in padded LDS. 16 MFMA : 8 ds_read per ks.
__global__ __launch_bounds__(256) void svd_gemm(
    const float* __restrict__ Pq, const float* __restrict__ Pk, const float* __restrict__ Pv,
    const __hip_bfloat16* __restrict__ VTq, const __hip_bfloat16* __restrict__ VTk,
    const __hip_bfloat16* __restrict__ VTv,
    const float* __restrict__ bq, const float* __restrict__ bk, const float* __restrict__ bv,
    const int* __restrict__ pos_ids,
    __hip_bfloat16* __restrict__ qout, __hip_bfloat16* __restrict__ kout,
    __hip_bfloat16* __restrict__ vTout)
{
    const int which = blockIdx.z;
    const float* P           = (which == 0) ? Pq : (which == 1) ? Pk : Pv;
    const __hip_bfloat16* VT = (which == 0) ? VTq : (which == 1) ? VTk : VTv;
    const float* bias        = (which == 0) ? bq : (which == 1) ? bk : bv;

    const int hg  = blockIdx.y;               // head group: heads hg*2, hg*2+1
    const int bm0 = blockIdx.x * 128;         // flattened b*M + m
    const int b   = bm0 >> 10;
    const int m0  = bm0 & 1023;
    const int tid = threadIdx.x;
    const int lane = tid & 63;
    const int w    = tid >> 6;
    const int l15  = lane & 15;
    const int quad = lane >> 4;

    __shared__ alignas(16) short Bs[128 * 136];           // V^T chunk [128 d][136], 34.8 KB

    f32x4 acc[16];                                        // [dt]: 2 mt folded below
    f32x4 acc2[16];
    #pragma unroll
    for (int dt = 0; dt < 16; ++dt) {
        acc[dt]  = (f32x4){0.f, 0.f, 0.f, 0.f};
        acc2[dt] = (f32x4){0.f, 0.f, 0.f, 0.f};
    }

    const float* prow0 = P + (size_t)(bm0 + w * 32 + l15) * RR;        // mt=0 row
    const float* prow1 = P + (size_t)(bm0 + w * 32 + 16 + l15) * RR;   // mt=1 row

    #pragma unroll
    for (int kc = 0; kc < 2; ++kc) {
        // ---- stage B: VT 128 x 128-k chunk (8 uint4 / thread) ----
        #pragma unroll
        for (int i = 0; i < 8; ++i) {
            int u   = tid + i * 256;          // 0..2047: 128 rows x 16 b128 units
            int row = u >> 4;
            int cg  = (u & 15) * 8;
            *(uint4*)&Bs[row * 136 + cg] =
                *(const uint4*)((const short*)VT + (size_t)(hg * 128 + row) * RR + kc * 128 + cg);
        }
        __syncthreads();

        #pragma unroll
        for (int ks = 0; ks < 4; ++ks) {
            const int ko = kc * 128 + ks * 32 + quad * 8;
            // A-frags direct from fp32 P (8 consecutive floats = 2 dwordx4)
            float4 a0lo = *(const float4*)(prow0 + ko);
            float4 a0hi = *(const float4*)(prow0 + ko + 4);
            float4 a1lo = *(const float4*)(prow1 + ko);
            float4 a1hi = *(const float4*)(prow1 + ko + 4);
            union { unsigned u[4]; short8 s; } pa0, pa1;
            pa0.u[0] = pack_bf16_rh(a0lo.x, a0lo.y);
            pa0.u[1] = pack_bf16_rh(a0lo.z, a0lo.w);
            pa0.u[2] = pack_bf16_rh(a0hi.x, a0hi.y);
            pa0.u[3] = pack_bf16_rh(a0hi.z, a0hi.w);
            pa1.u[0] = pack_bf16_rh(a1lo.x, a1lo.y);
            pa1.u[1] = pack_bf16_rh(a1lo.z, a1lo.w);
            pa1.u[2] = pack_bf16_rh(a1hi.x, a1hi.y);
            pa1.u[3] = pack_bf16_rh(a1hi.z, a1hi.w);

            #pragma unroll
            for (int dt = 0; dt < 8; ++dt) {
                short8 bf = *(const short8*)&Bs[(dt * 16 + l15) * 136 + ks * 32 + quad * 8];
                acc[kc * 8 + dt]  = __builtin_amdgcn_mfma_f32_16x16x32_bf16(pa0.s, bf, acc[kc * 8 + dt], 0, 0, 0);
                acc2[kc * 8 + dt] = __builtin_amdgcn_mfma_f32_16x16x32_bf16(pa1.s, bf, acc2[kc * 8 + dt], 0, 0, 0);
            }
        }
        __syncthreads();
    }
    // fold the two kc-partials (dt covers the same 128 d in both halves)
    #pragma unroll
    for (int dt = 0; dt < 8; ++dt) {
        #pragma unroll
        for (int r = 0; r < 4; ++r) {
            acc[dt][r]  += acc[8 + dt][r];
            acc2[dt][r] += acc2[8 + dt][r];
        }
    }

    // ---- bias ----
    #pragma unroll
    for (int dt = 0; dt < 8; ++dt) {
        float bc = bias[hg * 128 + dt * 16 + l15];
        #pragma unroll
        for (int r = 0; r < 4; ++r) { acc[dt][r] += bc; acc2[dt][r] += bc; }
    }

    if (which < 2) {
        __hip_bfloat16* out = (which == 0) ? qout : kout;
        int pm0[4], pm1[4];
        #pragma unroll
        for (int r = 0; r < 4; ++r) {
            pm0[r] = pos_ids[bm0 + w * 32 + quad * 4 + r];
            pm1[r] = pos_ids[bm0 + w * 32 + 16 + quad * 4 + r];
        }
        float cB[2][2][4], sB[2][2][4];                    // [freq-half][mt][r]
        #pragma unroll
        for (int f2 = 0; f2 < 2; ++f2) {
            float invf = __powf(10000.0f, -(float)(f2 * 16 + l15) * (1.0f / 32.0f));
            #pragma unroll
            for (int r = 0; r < 4; ++r) {
                __sincosf((float)pm0[r] * invf, &sB[f2][0][r], &cB[f2][0][r]);
                __sincosf((float)pm1[r] * invf, &sB[f2][1][r], &cB[f2][1][r]);
            }
        }
        #pragma unroll
        for (int dt = 0; dt < 8; ++dt) {
            const int h  = hg * 2 + (dt >> 2);
            const int cd = (dt & 3) * 16 + l15;
            const int f2 = dt & 1;
            #pragma unroll
            for (int r = 0; r < 4; ++r) {
                {   // mt = 0
                    float x  = acc[dt][r], xp = acc[dt ^ 2][r];
                    float c = cB[f2][0][r], s = sB[f2][0][r];
                    float val = ((dt & 3) < 2) ? (x * c - xp * s) : (xp * s + x * c);
                    int m = m0 + w * 32 + quad * 4 + r;
                    out[(((size_t)b * HH + h) * MM + m) * DHH + cd] = __float2bfloat16(val);
                }
                {   // mt = 1
                    float x  = acc2[dt][r], xp = acc2[dt ^ 2][r];
                    float c = cB[f2][1][r], s = sB[f2][1][r];
                    float val = ((dt & 3) < 2) ? (x * c - xp * s) : (xp * s + x * c);
                    int m = m0 + w * 32 + 16 + quad * 4 + r;
                    out[(((size_t)b * HH + h) * MM + m) * DHH + cd] = __float2bfloat16(val);
                }
            }
        }
    } else {
        // v: transpose 128 d x 128 m through LDS (reuse Bs) -> [b][h][d][m] bf16
        short* Tt = Bs;                                    // [128][136]
        __syncthreads();
        #pragma unroll
        for (int dt = 0; dt < 8; ++dt) {
            uint2 pk;
            pk.x = pack_bf16_rh(acc[dt][0], acc[dt][1]);
            pk.y = pack_bf16_rh(acc[dt][2], acc[dt][3]);
            *(uint2*)&Tt[(dt * 16 + l15) * 136 + w * 32 + quad * 4] = pk;
            pk.x = pack_bf16_rh(acc2[dt][0], acc2[dt][1]);
            pk.y = pack_bf16_rh(acc2[dt][2], acc2[dt][3]);
            *(uint2*)&Tt[(dt * 16 + l15) * 136 + w * 32 + 16 + quad * 4] = pk;
        }
        __syncthreads();
        #pragma unroll
        for (int i = 0; i < 8; ++i) {
            int u   = tid + i * 256;          // 0..2047: 128 rows x 16 segs
            int row = u >> 4;                 // d-local 0..127
            int seg = u & 15;
            int h   = hg * 2 + (row >> 6);
            int din = row & 63;
            *(uint4*)&vTout[(((size_t)b * HH + h) * DHH + din) * MM + m0 + seg * 8] =
                *(const uint4*)&Tt[row * 136 + seg * 8];
        }
    }
}

// ---------------- Kernel C: flash attention v3 (unchanged from R7) ----------------
// grid = 512: blockIdx = qt*64 + bh; wave = 32 queries; 128-key chunks.
__global__ __launch_bounds__(256, 2) void attn_kernel(
    const __hip_bfloat16* __restrict__ q, const __hip_bfloat16* __restrict__ k,
    const __hip_bfloat16* __restrict__ vT,
    const int* __restrict__ mask, float* __restrict__ out)
{
    const int bh   = blockIdx.x & 63;
    const int qt   = blockIdx.x >> 6;         // 0..7
    const int b    = bh >> 4;
    const int tid  = threadIdx.x;
    const int lane = tid & 63;
    const int w    = tid >> 6;
    const int l15  = lane & 15;
    const int quad = lane >> 4;
    const int q0   = qt * 128;

    __shared__ alignas(16) __hip_bfloat16 Kt[128][72];
    __shared__ alignas(16) __hip_bfloat16 Vt[64][136];

    const short* kbase = (const short*)k  + (size_t)bh * MM * DHH;
    const short* vbase = (const short*)vT + (size_t)bh * DHH * MM;

    short8 qa[2][2];
    #pragma unroll
    for (int mt = 0; mt < 2; ++mt) {
        const short* qb = (const short*)q +
            ((size_t)bh * MM + q0 + w * 32 + mt * 16 + l15) * DHH + quad * 8;
        qa[mt][0] = *(const short8*)(qb);
        qa[mt][1] = *(const short8*)(qb + 32);
    }

    f32x4 Ot[2][4];
    #pragma unroll
    for (int mt = 0; mt < 2; ++mt)
        #pragma unroll
        for (int dt = 0; dt < 4; ++dt) Ot[mt][dt] = (f32x4){0.f, 0.f, 0.f, 0.f};
    float lsum[2] = {0.f, 0.f};

    const int* maskb = mask + b * MM;
    const int srcbase = (lane & 48) | ((lane & 48) >> 2);
    const float k2 = 0.125f * 1.44269504089f;

    for (int nc = 0; nc < MM / 128; ++nc) {
        const int n0 = nc * 128;
        #pragma unroll
        for (int pass = 0; pass < 4; ++pass) {
            int u   = tid + pass * 256;
            int row = u >> 3;
            int cg  = u & 7;
            *(uint4*)&Kt[row][cg * 8] =
                *(const uint4*)(kbase + (size_t)(n0 + row) * DHH + cg * 8);
        }
        #pragma unroll
        for (int pass = 0; pass < 4; ++pass) {
            int u   = tid + pass * 256;
            int row = u >> 4;
            int c   = u & 15;
            union { uint4 q4; uint2 h2[2]; } vld;
            vld.q4 = *(const uint4*)(vbase + (size_t)row * MM + n0 + c * 8);
            int g  = c >> 3;
            int c6 = c & 7;
            int base0 = g * 64 + (c6 >> 2) * 32 + (c6 & 1) * 16 + ((c6 >> 1) & 1) * 4;
            *(uint2*)&Vt[row][base0]     = vld.h2[0];
            *(uint2*)&Vt[row][base0 + 8] = vld.h2[1];
        }
        __syncthreads();

        unsigned long long bal0 = __ballot(maskb[n0 + lane] != 0);
        unsigned long long bal1 = __ballot(maskb[n0 + 64 + lane] != 0);

        f32x4 S[2][8];
        #pragma unroll
        for (int t = 0; t < 8; ++t) {
            const short* kr = (const short*)&Kt[t * 16 + l15][quad * 8];
            short8 ka0 = *(const short8*)(kr);
            short8 ka1 = *(const short8*)(kr + 32);
            #pragma unroll
            for (int mt = 0; mt < 2; ++mt) {
                f32x4 c = (f32x4){0.f, 0.f, 0.f, 0.f};
                c = __builtin_amdgcn_mfma_f32_16x16x32_bf16(ka0, qa[mt][0], c, 0, 0, 0);
                c = __builtin_amdgcn_mfma_f32_16x16x32_bf16(ka1, qa[mt][1], c, 0, 0, 0);
                S[mt][t] = c;
            }
        }

        #pragma unroll
        for (int t = 0; t < 8; ++t) {
            unsigned bits = (unsigned)((t < 4 ? bal0 : bal1) >> ((t & 3) * 16 + quad * 4));
            #pragma unroll
            for (int r = 0; r < 4; ++r) {
                float sb = ((bits >> r) & 1u) ? 0.0f : -1e30f;
                #pragma unroll
                for (int mt = 0; mt < 2; ++mt) {
                    float e = EXP2F(fmaf(S[mt][t][r], k2, sb));
                    lsum[mt] += e;
                    S[mt][t][r] = e;
                }
            }
        }

        short8 pa[2][4];
        #pragma unroll
        for (int mt = 0; mt < 2; ++mt)
            #pragma unroll
            for (int p = 0; p < 4; ++p) {
                union { unsigned u[4]; short8 s; } pk;
                pk.u[0] = pack_bf16_rh(S[mt][2*p][0],   S[mt][2*p][1]);
                pk.u[1] = pack_bf16_rh(S[mt][2*p][2],   S[mt][2*p][3]);
                pk.u[2] = pack_bf16_rh(S[mt][2*p+1][0], S[mt][2*p+1][1]);
                pk.u[3] = pack_bf16_rh(S[mt][2*p+1][2], S[mt][2*p+1][3]);
                pa[mt][p] = pk.s;
            }

        #pragma unroll
        for (int p = 0; p < 4; ++p) {
            #pragma unroll
            for (int dt = 0; dt < 4; ++dt) {
                short8 vb = *(const short8*)&Vt[dt * 16 + l15][p * 32 + quad * 8];
                #pragma unroll
                for (int mt = 0; mt < 2; ++mt)
                    Ot[mt][dt] = __builtin_amdgcn_mfma_f32_16x16x32_bf16(pa[mt][p], vb, Ot[mt][dt], 0, 0, 0);
            }
        }
        __syncthreads();
    }

    #pragma unroll
    for (int mt = 0; mt < 2; ++mt) {
        float s = lsum[mt];
        s += __shfl_xor(s, 16, 64);
        s += __shfl_xor(s, 32, 64);
        float inv = 1.0f / s;
        float* ob = out + ((size_t)bh * MM + q0 + w * 32 + mt * 16) * DHH;
        #pragma unroll
        for (int r = 0; r < 4; ++r) {
            float ir = __shfl(inv, srcbase + r, 64);
            #pragma unroll
            for (int dt = 0; dt < 4; ++dt)
                ob[(quad * 4 + r) * DHH + dt * 16 + l15] = Ot[mt][dt][r] * ir;
        }
    }
}

extern "C" void kernel_launch(void* const* d_in, const int* in_sizes, int n_in,
                              void* d_out, int out_size, void* d_ws, size_t ws_size,
                              hipStream_t stream) {
    const float* Pq = (const float*)d_in[0];
    const float* Pk = (const float*)d_in[1];
    const float* Pv = (const float*)d_in[2];
    const float* Vq = (const float*)d_in[3];
    const float* Vk = (const float*)d_in[4];
    const float* Vv = (const float*)d_in[5];
    const float* bq = (const float*)d_in[6];
    const float* bk = (const float*)d_in[7];
    const float* bv = (const float*)d_in[8];
    const int* mask = (const int*)d_in[9];
    const int* pos  = (const int*)d_in[10];
    float* out = (float*)d_out;

    const size_t qkv_elems = (size_t)BB * HH * MM * DHH;
    __hip_bfloat16* qb  = (__hip_bfloat16*)d_ws;
    __hip_bfloat16* kb  = qb + qkv_elems;
    __hip_bfloat16* vT  = kb + qkv_elems;
    __hip_bfloat16* VTq = vT + qkv_elems;
    __hip_bfloat16* VTk = VTq + (size_t)DD * RR;
    __hip_bfloat16* VTv = VTk + (size_t)DD * RR;

    prep_kernel<<<768, 256, 0, stream>>>(Vq, Vk, Vv, VTq, VTk, VTv);

    dim3 gG(BB * MM / 128, HH / 2, 3);
    svd_gemm<<<gG, 256, 0, stream>>>(Pq, Pk, Pv, VTq, VTk, VTv, bq, bk, bv, pos,
                                     qb, kb, vT);

    attn_kernel<<<BB * HH * (MM / 128), 256, 0, stream>>>(qb, kb, vT, mask, out);
}

// Round 10
// 139.135 us; speedup vs baseline: 1.1238x; 1.0349x over previous
//
#include <hip/hip_runtime.h>
#include <hip/hip_bf16.h>
#include <math.h>

#define BB 4
#define MM 1024
#define RR 256
#define HH 16
#define DHH 64
#define DD (HH*DHH)   // 1024

typedef __attribute__((ext_vector_type(8))) short short8;   // 8 bf16 (MFMA A/B frag)
typedef __attribute__((ext_vector_type(4))) float f32x4;    // MFMA C/D frag

#if defined(__has_builtin)
#  if __has_builtin(__builtin_amdgcn_exp2f)
#    define EXP2F(x) __builtin_amdgcn_exp2f(x)
#  endif
#endif
#ifndef EXP2F
#  define EXP2F(x) __expf((x) * 0.6931471805599453f)
#endif

// pack two fp32 -> bf16x2 via round-half-up + v_perm (3 VALU total)
static __device__ __forceinline__ unsigned pack_bf16_rh(float a, float b) {
    unsigned ua = __builtin_bit_cast(unsigned, a) + 0x8000u;
    unsigned ub = __builtin_bit_cast(unsigned, b) + 0x8000u;
    return __builtin_amdgcn_perm(ub, ua, 0x07060302u);   // {lo=ua[31:16], hi=ub[31:16]}
}
static __device__ __forceinline__ unsigned short bf_rh(float a) {
    return (unsigned short)((__builtin_bit_cast(unsigned, a) + 0x8000u) >> 16);
}

// ---------------- Kernel A: V (R x d) fp32 -> VT (d x R) bf16 (unchanged) ----------
__global__ __launch_bounds__(256) void prep_kernel(
    const float* __restrict__ Vq, const float* __restrict__ Vk, const float* __restrict__ Vv,
    __hip_bfloat16* __restrict__ VTq, __hip_bfloat16* __restrict__ VTk,
    __hip_bfloat16* __restrict__ VTv)
{
    const int t   = threadIdx.x;
    const int z   = blockIdx.x / 256;
    const int rem = blockIdx.x % 256;
    const int r0  = (rem & 7) * 32;
    const int d0  = (rem >> 3) * 32;
    const float* V = (z == 0) ? Vq : (z == 1) ? Vk : Vv;
    __hip_bfloat16* VT = (z == 0) ? VTq : (z == 1) ? VTk : VTv;

    __shared__ __hip_bfloat16 Ts[32][33];
    {
        const int row = t >> 3;
        const int c4  = (t & 7) * 4;
        float4 f = *(const float4*)&V[(size_t)(r0 + row) * DD + d0 + c4];
        Ts[row][c4 + 0] = __float2bfloat16(f.x);
        Ts[row][c4 + 1] = __float2bfloat16(f.y);
        Ts[row][c4 + 2] = __float2bfloat16(f.z);
        Ts[row][c4 + 3] = __float2bfloat16(f.w);
    }
    __syncthreads();
    {
        const int orow = t >> 3;
        const int oc4  = (t & 7) * 4;
        union { unsigned short u[4]; uint2 v; } pk;
        #pragma unroll
        for (int i = 0; i < 4; ++i) pk.u[i] = *(unsigned short*)&Ts[oc4 + i][orow];
        *(uint2*)&VT[(size_t)(d0 + orow) * RR + r0 + oc4] = pk.v;
    }
}

// ---------------- Kernel B: MFMA projection v4 — high-occupancy ----------------
// grid (B*M/64, H/2, 3), block 256 (4 waves; wave w owns m-tile w). 64 m x 128 d
// (2 heads), K=256 in 4x64 chunks. LDS 18.4 KB -> ~6 blocks/CU resident.
__global__ __launch_bounds__(256, 4) void svd_gemm(
    const float* __restrict__ Pq, const float* __restrict__ Pk, const float* __restrict__ Pv,
    const __hip_bfloat16* __restrict__ VTq, const __hip_bfloat16* __restrict__ VTk,
    const __hip_bfloat16* __restrict__ VTv,
    const float* __restrict__ bq, const float* __restrict__ bk, const float* __restrict__ bv,
    const int* __restrict__ pos_ids,
    __hip_bfloat16* __restrict__ qout, __hip_bfloat16* __restrict__ kout,
    __hip_bfloat16* __restrict__ vTout)
{
    const int which = blockIdx.z;
    const float* P           = (which == 0) ? Pq : (which == 1) ? Pk : Pv;
    const __hip_bfloat16* VT = (which == 0) ? VTq : (which == 1) ? VTk : VTv;
    const float* bias        = (which == 0) ? bq : (which == 1) ? bk : bv;

    const int hg  = blockIdx.y;               // heads hg*2, hg*2+1
    const int bm0 = blockIdx.x * 64;
    const int b   = bm0 >> 10;
    const int m0  = bm0 & 1023;
    const int tid = threadIdx.x;
    const int lane = tid & 63;
    const int w    = tid >> 6;
    const int l15  = lane & 15;
    const int quad = lane >> 4;

    __shared__ alignas(16) short Bs[128 * 72];            // 18.4 KB

    f32x4 acc[8];
    #pragma unroll
    for (int dt = 0; dt < 8; ++dt) acc[dt] = (f32x4){0.f, 0.f, 0.f, 0.f};

    const float* prow = P + (size_t)(bm0 + w * 16 + l15) * RR;

    #pragma unroll
    for (int kc = 0; kc < 4; ++kc) {
        // stage VT 128 d x 64 k (4 uint4 / thread, coalesced)
        #pragma unroll
        for (int i = 0; i < 4; ++i) {
            int u   = tid + i * 256;          // 0..1023: 128 rows x 8 b128 units
            int row = u >> 3;
            int cg  = (u & 7) * 8;
            *(uint4*)&Bs[row * 72 + cg] =
                *(const uint4*)((const short*)VT + (size_t)(hg * 128 + row) * RR + kc * 64 + cg);
        }
        __syncthreads();

        #pragma unroll
        for (int ks = 0; ks < 2; ++ks) {
            const int ko = kc * 64 + ks * 32 + quad * 8;
            float4 alo = *(const float4*)(prow + ko);
            float4 ahi = *(const float4*)(prow + ko + 4);
            union { unsigned u[4]; short8 s; } pa;
            pa.u[0] = pack_bf16_rh(alo.x, alo.y);
            pa.u[1] = pack_bf16_rh(alo.z, alo.w);
            pa.u[2] = pack_bf16_rh(ahi.x, ahi.y);
            pa.u[3] = pack_bf16_rh(ahi.z, ahi.w);
            #pragma unroll
            for (int dt = 0; dt < 8; ++dt) {
                short8 bf = *(const short8*)&Bs[(dt * 16 + l15) * 72 + ks * 32 + quad * 8];
                acc[dt] = __builtin_amdgcn_mfma_f32_16x16x32_bf16(pa.s, bf, acc[dt], 0, 0, 0);
            }
        }
        __syncthreads();
    }

    // ---- bias ----
    #pragma unroll
    for (int dt = 0; dt < 8; ++dt) {
        float bc = bias[hg * 128 + dt * 16 + l15];
        #pragma unroll
        for (int r = 0; r < 4; ++r) acc[dt][r] += bc;
    }

    if (which < 2) {
        // ---- RoPE in-register, then coalesced store via LDS transpose ----
        __hip_bfloat16* out = (which == 0) ? qout : kout;
        int pm[4];
        #pragma unroll
        for (int r = 0; r < 4; ++r) pm[r] = pos_ids[bm0 + w * 16 + quad * 4 + r];
        float cB[2][4], sB[2][4];
        #pragma unroll
        for (int f2 = 0; f2 < 2; ++f2) {
            float invf = __powf(10000.0f, -(float)(f2 * 16 + l15) * (1.0f / 32.0f));
            #pragma unroll
            for (int r = 0; r < 4; ++r)
                __sincosf((float)pm[r] * invf, &sB[f2][r], &cB[f2][r]);
        }
        short* Ls = Bs;                        // [64 m][136]
        #pragma unroll
        for (int dt = 0; dt < 8; ++dt) {
            const int f2 = dt & 1;
            #pragma unroll
            for (int r = 0; r < 4; ++r) {
                float x  = acc[dt][r], xp = acc[dt ^ 2][r];
                float c = cB[f2][r], s = sB[f2][r];
                float val = ((dt & 3) < 2) ? (x * c - xp * s) : (xp * s + x * c);
                Ls[(w * 16 + quad * 4 + r) * 136 + dt * 16 + l15] = (short)bf_rh(val);
            }
        }
        __syncthreads();
        #pragma unroll
        for (int i = 0; i < 4; ++i) {
            int u   = tid + i * 256;           // 0..1023: 64 m x 2 hh x 8 segs
            int ml  = u >> 4;
            int hh  = (u >> 3) & 1;
            int seg = u & 7;
            *(uint4*)&out[(((size_t)b * HH + hg * 2 + hh) * MM + m0 + ml) * DHH + seg * 8] =
                *(const uint4*)&Ls[ml * 136 + hh * 64 + seg * 8];
        }
    } else {
        // ---- v: transpose 128 d x 64 m -> [b][h][d][m] bf16 ----
        short* Tt = Bs;                        // [128 d][72]
        #pragma unroll
        for (int dt = 0; dt < 8; ++dt) {
            uint2 pk;
            pk.x = pack_bf16_rh(acc[dt][0], acc[dt][1]);
            pk.y = pack_bf16_rh(acc[dt][2], acc[dt][3]);
            *(uint2*)&Tt[(dt * 16 + l15) * 72 + w * 16 + quad * 4] = pk;
        }
        __syncthreads();
        #pragma unroll
        for (int i = 0; i < 4; ++i) {
            int u   = tid + i * 256;           // 0..1023: 128 d-rows x 8 segs
            int row = u >> 3;
            int seg = u & 7;
            int h   = hg * 2 + (row >> 6);
            int din = row & 63;
            *(uint4*)&vTout[(((size_t)b * HH + h) * DHH + din) * MM + m0 + seg * 8] =
                *(const uint4*)&Tt[row * 72 + seg * 8];
        }
    }
}

// ---------------- Kernel C: flash attention v4 — split-K across waves ----------------
// grid = 1024: blockIdx = qt*64 + bh (qt 0..15 -> 64 queries/block; bh%8 XCD locality).
// Wave (mhalf,khalf): 32 queries x 64-key half of each 128-key chunk. No-max softmax
// makes partials additive: one LDS add-combine at the end.
__global__ __launch_bounds__(256, 4) void attn_kernel(
    const __hip_bfloat16* __restrict__ q, const __hip_bfloat16* __restrict__ k,
    const __hip_bfloat16* __restrict__ vT,
    const int* __restrict__ mask, float* __restrict__ out)
{
    const int bh    = blockIdx.x & 63;
    const int qt    = blockIdx.x >> 6;        // 0..15
    const int b     = bh >> 4;
    const int tid   = threadIdx.x;
    const int lane  = tid & 63;
    const int w     = tid >> 6;
    const int mhalf = w & 1;
    const int khalf = w >> 1;
    const int l15   = lane & 15;
    const int quad  = lane >> 4;
    const int q0    = qt * 64;
    const int koff  = khalf * 64;

    __shared__ alignas(16) __hip_bfloat16 Kt[128][72];    // 18.4 KB (reused for combine)
    __shared__ alignas(16) __hip_bfloat16 Vt[64][136];    // 17.4 KB, permuted n

    const short* kbase = (const short*)k  + (size_t)bh * MM * DHH;
    const short* vbase = (const short*)vT + (size_t)bh * DHH * MM;

    short8 qa[2][2];
    #pragma unroll
    for (int mt = 0; mt < 2; ++mt) {
        const short* qb = (const short*)q +
            ((size_t)bh * MM + q0 + mhalf * 32 + mt * 16 + l15) * DHH + quad * 8;
        qa[mt][0] = *(const short8*)(qb);
        qa[mt][1] = *(const short8*)(qb + 32);
    }

    f32x4 Ot[2][4];
    #pragma unroll
    for (int mt = 0; mt < 2; ++mt)
        #pragma unroll
        for (int dt = 0; dt < 4; ++dt) Ot[mt][dt] = (f32x4){0.f, 0.f, 0.f, 0.f};
    float lsum[2] = {0.f, 0.f};

    const int* maskb = mask + b * MM;
    const int srcbase = (lane & 48) | ((lane & 48) >> 2);
    const float k2 = 0.125f * 1.44269504089f;

    for (int nc = 0; nc < MM / 128; ++nc) {
        const int n0 = nc * 128;
        #pragma unroll
        for (int pass = 0; pass < 4; ++pass) {
            int u   = tid + pass * 256;
            int row = u >> 3;
            int cg  = u & 7;
            *(uint4*)&Kt[row][cg * 8] =
                *(const uint4*)(kbase + (size_t)(n0 + row) * DHH + cg * 8);
        }
        #pragma unroll
        for (int pass = 0; pass < 4; ++pass) {
            int u   = tid + pass * 256;
            int row = u >> 4;
            int c   = u & 15;
            union { uint4 q4; uint2 h2[2]; } vld;
            vld.q4 = *(const uint4*)(vbase + (size_t)row * MM + n0 + c * 8);
            int g  = c >> 3;
            int c6 = c & 7;
            int base0 = g * 64 + (c6 >> 2) * 32 + (c6 & 1) * 16 + ((c6 >> 1) & 1) * 4;
            *(uint2*)&Vt[row][base0]     = vld.h2[0];
            *(uint2*)&Vt[row][base0 + 8] = vld.h2[1];
        }
        __syncthreads();

        unsigned long long bal = __ballot(maskb[n0 + koff + lane] != 0);

        // ---- S^T = K·Q^T over this wave's 64-key half ----
        f32x4 S[2][4];
        #pragma unroll
        for (int t = 0; t < 4; ++t) {
            const short* kr = (const short*)&Kt[koff + t * 16 + l15][quad * 8];
            short8 ka0 = *(const short8*)(kr);
            short8 ka1 = *(const short8*)(kr + 32);
            #pragma unroll
            for (int mt = 0; mt < 2; ++mt) {
                f32x4 c = (f32x4){0.f, 0.f, 0.f, 0.f};
                c = __builtin_amdgcn_mfma_f32_16x16x32_bf16(ka0, qa[mt][0], c, 0, 0, 0);
                c = __builtin_amdgcn_mfma_f32_16x16x32_bf16(ka1, qa[mt][1], c, 0, 0, 0);
                S[mt][t] = c;
            }
        }

        #pragma unroll
        for (int t = 0; t < 4; ++t) {
            unsigned bits = (unsigned)(bal >> (t * 16 + quad * 4));
            #pragma unroll
            for (int r = 0; r < 4; ++r) {
                float sb = ((bits >> r) & 1u) ? 0.0f : -1e30f;
                #pragma unroll
                for (int mt = 0; mt < 2; ++mt) {
                    float e = EXP2F(fmaf(S[mt][t][r], k2, sb));
                    lsum[mt] += e;
                    S[mt][t][r] = e;
                }
            }
        }

        short8 pa[2][2];
        #pragma unroll
        for (int mt = 0; mt < 2; ++mt)
            #pragma unroll
            for (int p = 0; p < 2; ++p) {
                union { unsigned u[4]; short8 s; } pk;
                pk.u[0] = pack_bf16_rh(S[mt][2*p][0],   S[mt][2*p][1]);
                pk.u[1] = pack_bf16_rh(S[mt][2*p][2],   S[mt][2*p][3]);
                pk.u[2] = pack_bf16_rh(S[mt][2*p+1][0], S[mt][2*p+1][1]);
                pk.u[3] = pack_bf16_rh(S[mt][2*p+1][2], S[mt][2*p+1][3]);
                pa[mt][p] = pk.s;
            }

        #pragma unroll
        for (int p = 0; p < 2; ++p) {
            #pragma unroll
            for (int dt = 0; dt < 4; ++dt) {
                short8 vb = *(const short8*)&Vt[dt * 16 + l15][koff + p * 32 + quad * 8];
                #pragma unroll
                for (int mt = 0; mt < 2; ++mt)
                    Ot[mt][dt] = __builtin_amdgcn_mfma_f32_16x16x32_bf16(pa[mt][p], vb, Ot[mt][dt], 0, 0, 0);
            }
        }
        __syncthreads();
    }

    // ---- combine the two key-halves (plain add: no-max softmax) ----
    float* C = (float*)&Kt[0][0];              // 128 lanes x 34 slots = 17.4 KB
    const int cb = (mhalf * 64 + lane) * 34;
    if (khalf == 1) {
        #pragma unroll
        for (int mt = 0; mt < 2; ++mt) {
            #pragma unroll
            for (int dt = 0; dt < 4; ++dt)
                #pragma unroll
                for (int r = 0; r < 4; ++r)
                    C[cb + mt * 16 + dt * 4 + r] = Ot[mt][dt][r];
            C[cb + 32 + mt] = lsum[mt];
        }
    }
    __syncthreads();
    if (khalf == 0) {
        #pragma unroll
        for (int mt = 0; mt < 2; ++mt) {
            #pragma unroll
            for (int dt = 0; dt < 4; ++dt)
                #pragma unroll
                for (int r = 0; r < 4; ++r)
                    Ot[mt][dt][r] += C[cb + mt * 16 + dt * 4 + r];
            lsum[mt] += C[cb + 32 + mt];
        }
        #pragma unroll
        for (int mt = 0; mt < 2; ++mt) {
            float s = lsum[mt];
            s += __shfl_xor(s, 16, 64);
            s += __shfl_xor(s, 32, 64);
            float inv = 1.0f / s;
            float* ob = out + ((size_t)bh * MM + q0 + mhalf * 32 + mt * 16) * DHH;
            #pragma unroll
            for (int r = 0; r < 4; ++r) {
                float ir = __shfl(inv, srcbase + r, 64);
                #pragma unroll
                for (int dt = 0; dt < 4; ++dt)
                    ob[(quad * 4 + r) * DHH + dt * 16 + l15] = Ot[mt][dt][r] * ir;
            }
        }
    }
}

extern "C" void kernel_launch(void* const* d_in, const int* in_sizes, int n_in,
                              void* d_out, int out_size, void* d_ws, size_t ws_size,
                              hipStream_t stream) {
    const float* Pq = (const float*)d_in[0];
    const float* Pk = (const float*)d_in[1];
    const float* Pv = (const float*)d_in[2];
    const float* Vq = (const float*)d_in[3];
    const float* Vk = (const float*)d_in[4];
    const float* Vv = (const float*)d_in[5];
    const float* bq = (const float*)d_in[6];
    const float* bk = (const float*)d_in[7];
    const float* bv = (const float*)d_in[8];
    const int* mask = (const int*)d_in[9];
    const int* pos  = (const int*)d_in[10];
    float* out = (float*)d_out;

    const size_t qkv_elems = (size_t)BB * HH * MM * DHH;
    __hip_bfloat16* qb  = (__hip_bfloat16*)d_ws;
    __hip_bfloat16* kb  = qb + qkv_elems;
    __hip_bfloat16* vT  = kb + qkv_elems;
    __hip_bfloat16* VTq = vT + qkv_elems;
    __hip_bfloat16* VTk = VTq + (size_t)DD * RR;
    __hip_bfloat16* VTv = VTk + (size_t)DD * RR;

    prep_kernel<<<768, 256, 0, stream>>>(Vq, Vk, Vv, VTq, VTk, VTv);

    dim3 gG(BB * MM / 64, HH / 2, 3);
    svd_gemm<<<gG, 256, 0, stream>>>(Pq, Pk, Pv, VTq, VTk, VTv, bq, bk, bv, pos,
                                     qb, kb, vT);

    attn_kernel<<<BB * HH * (MM / 64), 256, 0, stream>>>(qb, kb, vT, mask, out);
}